// Round 1
// 798.303 us; speedup vs baseline: 1.0133x; 1.0133x over previous
//
#include <hip/hip_runtime.h>

#define B_ 4
#define T_ 256
#define U_ 64
#define D_ 512    // ENC_DIM == PRED_DIM
#define W_LD 1024 // W leading dim
#define V_ 2048   // VOCAB

#define TT 16     // t rows per block
#define PAD 68    // LDS row stride in floats: 272 B (16B-aligned, bank-spreading)

typedef __attribute__((ext_vector_type(8))) __bf16 bf16x8;
typedef __attribute__((ext_vector_type(4))) float f32x4;

static __device__ inline bf16x8 load8_bf16(const float* __restrict__ p) {
    float4 a = *(const float4*)p;
    float4 b = *(const float4*)(p + 4);
    bf16x8 r;
    r[0] = (__bf16)a.x; r[1] = (__bf16)a.y; r[2] = (__bf16)a.z; r[3] = (__bf16)a.w;
    r[4] = (__bf16)b.x; r[5] = (__bf16)b.y; r[6] = (__bf16)b.z; r[7] = (__bf16)b.w;
    return r;
}

// Fused joint network: out[b,t,u,v] = enc[b,t,:]·W[v,:512] + pred[b,u,:]·W[v,512:] + bias[v]
// Block = (t-tile of 16, v-tile of 256, b). 4 waves; wave w owns v strip [vb*256+w*64, +64).
// Per-wave LDS slice holds enc_proj[16][64] and a 32-u chunk of pred_proj — no barriers at all.
__global__ __launch_bounds__(256) void joint_fused(
        const float* __restrict__ enc, const float* __restrict__ pred,
        const float* __restrict__ W, const float* __restrict__ bias,
        float* __restrict__ out) {
    const int wave = threadIdx.x >> 6;
    const int lane = threadIdx.x & 63;
    const int quad = lane >> 4;      // 0..3
    const int l16  = lane & 15;

    const int tb = blockIdx.x;       // 0..15
    const int vb = blockIdx.y;       // 0..7
    const int b  = blockIdx.z;       // 0..3
    const int t0 = tb * TT;
    const int nbase = vb * 256 + wave * 64;   // wave's global v base

    __shared__ float lds[4 * (TT + 32) * PAD];          // 52,224 B
    float* encS  = lds + wave * (TT + 32) * PAD;        // [TT][PAD]
    float* predS = encS + TT * PAD;                     // [32][PAD]

    // ---- enc GEMM: 16 rows x 64 cols x K=512, bias fused into staging ----
    {
        const float* arow = enc + (size_t)(b * T_ + t0 + l16) * D_;
        f32x4 acc[4];
        #pragma unroll
        for (int j = 0; j < 4; ++j) acc[j] = (f32x4){0.f, 0.f, 0.f, 0.f};
        #pragma unroll 4
        for (int ks = 0; ks < 16; ++ks) {
            const int k = ks * 32 + quad * 8;
            bf16x8 af = load8_bf16(arow + k);
            #pragma unroll
            for (int j = 0; j < 4; ++j) {
                bf16x8 bfr = load8_bf16(W + (size_t)(nbase + j * 16 + l16) * W_LD + k);
                acc[j] = __builtin_amdgcn_mfma_f32_16x16x32_bf16(af, bfr, acc[j], 0, 0, 0);
            }
        }
        // C/D layout: col = l16 (v = nbase + j*16 + l16), row = quad*4 + r
        #pragma unroll
        for (int j = 0; j < 4; ++j) {
            const float bs = bias[nbase + j * 16 + l16];
            #pragma unroll
            for (int r = 0; r < 4; ++r)
                encS[(quad * 4 + r) * PAD + j * 16 + l16] = acc[j][r] + bs;
        }
    }

    // ---- pred GEMM + store, in two 32-u chunks (keeps LDS at 52 KB) ----
    const float* wpred = W + D_;
    for (int c = 0; c < 2; ++c) {
        #pragma unroll
        for (int h = 0; h < 2; ++h) {
            const int u0 = c * 32 + h * 16;
            const float* prow = pred + (size_t)(b * U_ + u0 + l16) * D_;
            f32x4 pacc[4];
            #pragma unroll
            for (int j = 0; j < 4; ++j) pacc[j] = (f32x4){0.f, 0.f, 0.f, 0.f};
            #pragma unroll 4
            for (int ks = 0; ks < 16; ++ks) {
                const int k = ks * 32 + quad * 8;
                bf16x8 af = load8_bf16(prow + k);
                #pragma unroll
                for (int j = 0; j < 4; ++j) {
                    bf16x8 bfr = load8_bf16(wpred + (size_t)(nbase + j * 16 + l16) * W_LD + k);
                    pacc[j] = __builtin_amdgcn_mfma_f32_16x16x32_bf16(af, bfr, pacc[j], 0, 0, 0);
                }
            }
            #pragma unroll
            for (int j = 0; j < 4; ++j)
                #pragma unroll
                for (int r = 0; r < 4; ++r)
                    predS[(h * 16 + quad * 4 + r) * PAD + j * 16 + l16] = pacc[j][r];
        }

        // epilogue for u in [c*32, c*32+32): quad picks u%4, l16 picks 4 v.
        // Per instruction: 4 u-rows x 256 B contiguous stores; enc LDS read is a
        // quad-broadcast (free), pred LDS read spreads evenly over banks (PAD=68).
        float* outb = out + ((size_t)(b * T_ + t0) * U_ + c * 32 + quad) * V_
                          + nbase + l16 * 4;
        for (int t = 0; t < TT; ++t) {
            const float4 ev = *(const float4*)(encS + t * PAD + l16 * 4);
            float* orow = outb + (size_t)t * U_ * V_;
            #pragma unroll 8
            for (int ui = 0; ui < 8; ++ui) {
                const float4 pv = *(const float4*)(predS + (ui * 4 + quad) * PAD + l16 * 4);
                float4 o;
                o.x = ev.x + pv.x; o.y = ev.y + pv.y;
                o.z = ev.z + pv.z; o.w = ev.w + pv.w;
                *(float4*)(orow + (size_t)ui * 4 * V_) = o;
            }
        }
    }
}

extern "C" void kernel_launch(void* const* d_in, const int* in_sizes, int n_in,
                              void* d_out, int out_size, void* d_ws, size_t ws_size,
                              hipStream_t stream) {
    const float* enc  = (const float*)d_in[0];
    const float* pred = (const float*)d_in[1];
    const float* W    = (const float*)d_in[2];
    const float* bias = (const float*)d_in[3];
    float* out = (float*)d_out;

    dim3 grid(16, 8, 4);   // (t-tiles, v-tiles, b)
    joint_fused<<<grid, dim3(256), 0, stream>>>(enc, pred, W, bias, out);
}

// Round 2
// 596.486 us; speedup vs baseline: 1.3561x; 1.3383x over previous
//
#include <hip/hip_runtime.h>

#define B_ 4
#define T_ 256
#define U_ 64
#define D_ 512    // ENC_DIM == PRED_DIM
#define W_LD 1024 // W leading dim (ENC_DIM+PRED_DIM)
#define V_ 2048   // VOCAB
#define MROWS 1280 // 1024 enc rows + 256 pred rows

typedef __attribute__((ext_vector_type(8))) __bf16 bf16x8;
typedef __attribute__((ext_vector_type(4))) float f32x4;

static __device__ inline bf16x8 load8_bf16(const float* __restrict__ p) {
    float4 a = *(const float4*)p;
    float4 b = *(const float4*)(p + 4);
    bf16x8 r;
    r[0] = (__bf16)a.x; r[1] = (__bf16)a.y; r[2] = (__bf16)a.z; r[3] = (__bf16)a.w;
    r[4] = (__bf16)b.x; r[5] = (__bf16)b.y; r[6] = (__bf16)b.z; r[7] = (__bf16)b.w;
    return r;
}

// Phase A: proj[m][v] = sum_k X[m][k] * Wpart[v][k]   (+ bias for pred rows)
//   rows 0..1023   : X = enc_out (b*T+t), Wpart = W[:, 0:512]
//   rows 1024..1279: X = pred_out (b*U+u), Wpart = W[:, 512:1024], += bias[v]
__global__ __launch_bounds__(256) void proj_gemm(
        const float* __restrict__ enc, const float* __restrict__ pred,
        const float* __restrict__ W, const float* __restrict__ bias,
        float* __restrict__ proj) {
    const int wave = threadIdx.x >> 6;
    const int lane = threadIdx.x & 63;
    const int quad = lane >> 4;     // 0..3
    const int l16  = lane & 15;
    const int mtile = blockIdx.y;   // 16 rows
    const int nbase = blockIdx.x * 256 + wave * 64;

    const int mrow = mtile * 16 + l16;
    const float* arow;
    const float* wbase;
    if (mrow < 1024) { arow = enc  + (size_t)mrow * D_;          wbase = W; }
    else             { arow = pred + (size_t)(mrow - 1024) * D_; wbase = W + D_; }

    f32x4 acc[4];
    #pragma unroll
    for (int j = 0; j < 4; ++j) acc[j] = (f32x4){0.f, 0.f, 0.f, 0.f};

    #pragma unroll 4
    for (int ks = 0; ks < 16; ++ks) {           // K = 512 = 16 * 32
        const int k = ks * 32 + quad * 8;
        bf16x8 af = load8_bf16(arow + k);
        #pragma unroll
        for (int j = 0; j < 4; ++j) {
            const float* wp = wbase + (size_t)(nbase + j * 16 + l16) * W_LD + k;
            bf16x8 bf = load8_bf16(wp);
            acc[j] = __builtin_amdgcn_mfma_f32_16x16x32_bf16(af, bf, acc[j], 0, 0, 0);
        }
    }

    // C/D layout: col = lane&15, row = (lane>>4)*4 + reg
    const int mb = mtile * 16 + quad * 4;
    const bool isPred = (mb >= 1024);           // uniform per block-row tile
    #pragma unroll
    for (int j = 0; j < 4; ++j) {
        const int v = nbase + j * 16 + l16;
        const float bs = isPred ? bias[v] : 0.0f;
        #pragma unroll
        for (int r = 0; r < 4; ++r)
            proj[(size_t)(mb + r) * V_ + v] = acc[j][r] + bs;
    }
}

// Phase B: out[b,t,u,v] = enc_proj[b,t,v] + (pred_proj+bias)[b,u,v]
// Block = (b, t, u-group of 8). Per thread: 8 enc floats + 64 pred floats into
// REGISTERS first (single descending vmcnt chain, no stores outstanding), then
// 16 fire-and-forget float4 stores. Stores never wait on vmcnt -> fill-like
// write stream. 64 KB contiguous out per block; grid 8192 keeps ~20+ waves/CU.
__global__ __launch_bounds__(256) void bcast_add2(
        const float* __restrict__ proj, float* __restrict__ out) {
    const int gid = blockIdx.x;
    const int ug  = gid & 7;         // u-group: u = ug*8 .. ug*8+7
    const int row = gid >> 3;        // b*T + t
    const int b   = row >> 8;
    const int v0  = threadIdx.x * 8;

    const float* erow = proj + (size_t)row * V_ + v0;
    const float* prow = proj + (size_t)(1024 + b * U_ + ug * 8) * V_ + v0;

    float4 e0 = *(const float4*)erow;
    float4 e1 = *(const float4*)(erow + 4);

    float4 p0[8], p1[8];
    #pragma unroll
    for (int u = 0; u < 8; ++u) {
        p0[u] = *(const float4*)(prow + (size_t)u * V_);
        p1[u] = *(const float4*)(prow + (size_t)u * V_ + 4);
    }

    float* orow = out + ((size_t)row * U_ + ug * 8) * V_ + v0;
    #pragma unroll
    for (int u = 0; u < 8; ++u) {
        float4 o0 = make_float4(e0.x + p0[u].x, e0.y + p0[u].y,
                                e0.z + p0[u].z, e0.w + p0[u].w);
        float4 o1 = make_float4(e1.x + p1[u].x, e1.y + p1[u].y,
                                e1.z + p1[u].z, e1.w + p1[u].w);
        *(float4*)(orow + (size_t)u * V_)     = o0;
        *(float4*)(orow + (size_t)u * V_ + 4) = o1;
    }
}

extern "C" void kernel_launch(void* const* d_in, const int* in_sizes, int n_in,
                              void* d_out, int out_size, void* d_ws, size_t ws_size,
                              hipStream_t stream) {
    const float* enc  = (const float*)d_in[0];
    const float* pred = (const float*)d_in[1];
    const float* W    = (const float*)d_in[2];
    const float* bias = (const float*)d_in[3];
    float* out  = (float*)d_out;
    float* proj = (float*)d_ws;   // MROWS * V_ * 4 = 10.5 MB

    dim3 gA(V_ / 256, MROWS / 16);       // (8, 80)
    proj_gemm<<<gA, dim3(256), 0, stream>>>(enc, pred, W, bias, proj);
    bcast_add2<<<dim3(B_ * T_ * (U_ / 8)), dim3(256), 0, stream>>>(proj, out);
}